// Round 1
// baseline (248.485 us; speedup 1.0000x reference)
//
#include <hip/hip_runtime.h>
#include <hip/hip_bf16.h>
#include <math.h>

#define NNODES 8192

// ---------------------------------------------------------------------------
// x0 build: x0[i] = {dist_from_prev[i], dist_to_start[i]}
// ---------------------------------------------------------------------------
__global__ __launch_bounds__(256) void build_x0_kernel(
    const float* __restrict__ dfp, const float* __restrict__ dts,
    float* __restrict__ x0) {
  int i = blockIdx.x * 256 + threadIdx.x;
  if (i < NNODES) {
    x0[2 * i + 0] = dfp[i];
    x0[2 * i + 1] = dts[i];
  }
}

// ---------------------------------------------------------------------------
// Aggregation: h = adj @ x   (adj [N][N] f32 row-major, x [N][K], h [N][K])
// Block = 256 threads = 4 waves. Each wave owns 4 rows -> 16 rows/block.
// Lanes split the k dimension; x chunk (256 x K) is register-staged per wave
// and reused across the wave's 4 rows. Butterfly reduce at the end.
// ---------------------------------------------------------------------------
template <int K>
__global__ __launch_bounds__(256) void agg_kernel(
    const float* __restrict__ adj, const float* __restrict__ x,
    float* __restrict__ h) {
  const int wave = threadIdx.x >> 6;
  const int lane = threadIdx.x & 63;
  const int row0 = blockIdx.x * 16 + wave * 4;

  float acc[4][K];
#pragma unroll
  for (int r = 0; r < 4; ++r)
#pragma unroll
    for (int j = 0; j < K; ++j) acc[r][j] = 0.f;

  for (int k0 = 0; k0 < NNODES; k0 += 256) {
    // register-stage x[k0 + lane + 64u][0..K)
    float xr[4][K];
#pragma unroll
    for (int u = 0; u < 4; ++u) {
      const float* xp = x + (size_t)(k0 + lane + 64 * u) * K;
      if constexpr (K == 8) {
        float4 a = *(const float4*)xp;
        float4 b = *(const float4*)(xp + 4);
        xr[u][0] = a.x; xr[u][1] = a.y; xr[u][2] = a.z; xr[u][3] = a.w;
        xr[u][4] = b.x; xr[u][5] = b.y; xr[u][6] = b.z; xr[u][7] = b.w;
      } else {
        float2 a = *(const float2*)xp;
        xr[u][0] = a.x; xr[u][1] = a.y;
      }
    }
#pragma unroll
    for (int r = 0; r < 4; ++r) {
      const float* ap = adj + (size_t)(row0 + r) * NNODES + k0 + lane;
#pragma unroll
      for (int u = 0; u < 4; ++u) {
        float a = ap[64 * u];
#pragma unroll
        for (int j = 0; j < K; ++j) acc[r][j] = fmaf(a, xr[u][j], acc[r][j]);
      }
    }
  }

#pragma unroll
  for (int r = 0; r < 4; ++r) {
#pragma unroll
    for (int j = 0; j < K; ++j) {
      float v = acc[r][j];
#pragma unroll
      for (int off = 32; off > 0; off >>= 1) v += __shfl_xor(v, off, 64);
      if (lane == 0) h[(size_t)(row0 + r) * K + j] = v;
    }
  }
}

// ---------------------------------------------------------------------------
// Per-node 2-layer MLP with outer relu (hidden GIN layers):
// out = relu( relu(h @ W1 + b1) @ W2 + b2 ),  h [N][DIN], out [N][8]
// ---------------------------------------------------------------------------
template <int DIN>
__global__ __launch_bounds__(256) void mlp_kernel(
    const float* __restrict__ h, const float* __restrict__ W1,
    const float* __restrict__ b1, const float* __restrict__ W2,
    const float* __restrict__ b2, float* __restrict__ out) {
  int i = blockIdx.x * 256 + threadIdx.x;
  if (i >= NNODES) return;

  float hv[DIN];
#pragma unroll
  for (int d = 0; d < DIN; ++d) hv[d] = h[(size_t)i * DIN + d];

  float z[8];
#pragma unroll
  for (int j = 0; j < 8; ++j) {
    float s = b1[j];
#pragma unroll
    for (int d = 0; d < DIN; ++d) s = fmaf(hv[d], W1[d * 8 + j], s);
    z[j] = fmaxf(s, 0.f);
  }
#pragma unroll
  for (int o = 0; o < 8; ++o) {
    float s = b2[o];
#pragma unroll
    for (int j = 0; j < 8; ++j) s = fmaf(z[j], W2[j * 8 + o], s);
    out[(size_t)i * 8 + o] = fmaxf(s, 0.f);
  }
}

// ---------------------------------------------------------------------------
// Heads: logits[i] = relu(h2[i]·W1p + b1p)·W2p + b2p ; value likewise.
// ---------------------------------------------------------------------------
__global__ __launch_bounds__(256) void heads_kernel(
    const float* __restrict__ h2,
    const float* __restrict__ W1p, const float* __restrict__ b1p,
    const float* __restrict__ W2p, const float* __restrict__ b2p,
    const float* __restrict__ W1v, const float* __restrict__ b1v,
    const float* __restrict__ W2v, const float* __restrict__ b2v,
    float* __restrict__ logits, float* __restrict__ value) {
  int i = blockIdx.x * 256 + threadIdx.x;
  if (i >= NNODES) return;
  float4 a = *(const float4*)(h2 + (size_t)i * 8);
  float4 b = *(const float4*)(h2 + (size_t)i * 8 + 4);
  float hv[8] = {a.x, a.y, a.z, a.w, b.x, b.y, b.z, b.w};
  float zp = b1p[0], zv = b1v[0];
#pragma unroll
  for (int d = 0; d < 8; ++d) {
    zp = fmaf(hv[d], W1p[d], zp);
    zv = fmaf(hv[d], W1v[d], zv);
  }
  zp = fmaxf(zp, 0.f);
  zv = fmaxf(zv, 0.f);
  logits[i] = fmaf(zp, W2p[0], b2p[0]);
  value[i]  = fmaf(zv, W2v[0], b2v[0]);
}

// ---------------------------------------------------------------------------
// Single-block reduction: max(logits), mean(value) [pass 1];
// sum(exp(l-max)), sum((v-mean)^2) [pass 2]. scal = {max, 1/sumexp, mean, 1/std}
// ---------------------------------------------------------------------------
__global__ __launch_bounds__(256) void reduce_kernel(
    const float* __restrict__ logits, const float* __restrict__ value,
    float* __restrict__ scal) {
  const int tid = threadIdx.x;
  const int wave = tid >> 6, lane = tid & 63;
  __shared__ float sa[4], sb[4];

  float m = -3.4e38f, s = 0.f;
  for (int i = tid; i < NNODES; i += 256) {
    m = fmaxf(m, logits[i]);
    s += value[i];
  }
#pragma unroll
  for (int off = 32; off > 0; off >>= 1) {
    m = fmaxf(m, __shfl_xor(m, off, 64));
    s += __shfl_xor(s, off, 64);
  }
  if (lane == 0) { sa[wave] = m; sb[wave] = s; }
  __syncthreads();
  m = fmaxf(fmaxf(sa[0], sa[1]), fmaxf(sa[2], sa[3]));
  s = sb[0] + sb[1] + sb[2] + sb[3];
  const float mean = s * (1.f / NNODES);
  __syncthreads();

  float e = 0.f, v2 = 0.f;
  for (int i = tid; i < NNODES; i += 256) {
    e += expf(logits[i] - m);
    float d = value[i] - mean;
    v2 = fmaf(d, d, v2);
  }
#pragma unroll
  for (int off = 32; off > 0; off >>= 1) {
    e += __shfl_xor(e, off, 64);
    v2 += __shfl_xor(v2, off, 64);
  }
  if (lane == 0) { sa[wave] = e; sb[wave] = v2; }
  __syncthreads();
  if (tid == 0) {
    e = sa[0] + sa[1] + sa[2] + sa[3];
    v2 = sb[0] + sb[1] + sb[2] + sb[3];
    scal[0] = m;
    scal[1] = 1.f / e;
    scal[2] = mean;
    scal[3] = 1.f / sqrtf(v2 * (1.f / NNODES) + 1e-10f);
  }
}

// ---------------------------------------------------------------------------
// Finalize in place on d_out: policy = exp(l-max)/sumexp ; nv = (v-mean)/std
// ---------------------------------------------------------------------------
__global__ __launch_bounds__(256) void finalize_kernel(
    float* __restrict__ out, const float* __restrict__ scal) {
  int i = blockIdx.x * 256 + threadIdx.x;
  if (i >= NNODES) return;
  float m = scal[0], inv_e = scal[1], mean = scal[2], inv_std = scal[3];
  out[i] = expf(out[i] - m) * inv_e;
  out[NNODES + i] = (out[NNODES + i] - mean) * inv_std;
}

// ---------------------------------------------------------------------------
extern "C" void kernel_launch(void* const* d_in, const int* in_sizes, int n_in,
                              void* d_out, int out_size, void* d_ws,
                              size_t ws_size, hipStream_t stream) {
  const float* adj = (const float*)d_in[0];
  const float* dfp = (const float*)d_in[1];
  const float* dts = (const float*)d_in[2];
  const float* W1_l0 = (const float*)d_in[3];
  const float* b1_l0 = (const float*)d_in[4];
  const float* W2_l0 = (const float*)d_in[5];
  const float* b2_l0 = (const float*)d_in[6];
  const float* W1_l1 = (const float*)d_in[7];
  const float* b1_l1 = (const float*)d_in[8];
  const float* W2_l1 = (const float*)d_in[9];
  const float* b2_l1 = (const float*)d_in[10];
  const float* W1_pol = (const float*)d_in[11];
  const float* b1_pol = (const float*)d_in[12];
  const float* W2_pol = (const float*)d_in[13];
  const float* b2_pol = (const float*)d_in[14];
  const float* W1_val = (const float*)d_in[15];
  const float* b1_val = (const float*)d_in[16];
  const float* W2_val = (const float*)d_in[17];
  const float* b2_val = (const float*)d_in[18];

  float* out = (float*)d_out;
  float* wsf = (float*)d_ws;
  float* bufA = wsf;                 // [N][8] (x0 packed as [N][2] initially)
  float* bufB = wsf + NNODES * 8;    // [N][8]
  float* scal = wsf + NNODES * 16;   // [4]
  float* logits = out;               // reuse d_out front half for raw logits
  float* value = out + NNODES;       // back half for raw values

  const int nblk = NNODES / 256;  // 32

  // x0 = stack(dfp, dts)
  build_x0_kernel<<<nblk, 256, 0, stream>>>(dfp, dts, bufA);
  // layer 0: h0 = adj @ x0 ; cur0 = relu(mlp_l0(h0))
  agg_kernel<2><<<NNODES / 16, 256, 0, stream>>>(adj, bufA, bufB);
  mlp_kernel<2><<<nblk, 256, 0, stream>>>(bufB, W1_l0, b1_l0, W2_l0, b2_l0, bufA);
  // layer 1
  agg_kernel<8><<<NNODES / 16, 256, 0, stream>>>(adj, bufA, bufB);
  mlp_kernel<8><<<nblk, 256, 0, stream>>>(bufB, W1_l1, b1_l1, W2_l1, b2_l1, bufA);
  // shared aggregation for pol + val heads
  agg_kernel<8><<<NNODES / 16, 256, 0, stream>>>(adj, bufA, bufB);
  heads_kernel<<<nblk, 256, 0, stream>>>(bufB, W1_pol, b1_pol, W2_pol, b2_pol,
                                         W1_val, b1_val, W2_val, b2_val,
                                         logits, value);
  reduce_kernel<<<1, 256, 0, stream>>>(logits, value, scal);
  finalize_kernel<<<nblk, 256, 0, stream>>>(out, scal);
}

// Round 2
// 160.004 us; speedup vs baseline: 1.5530x; 1.5530x over previous
//
#include <hip/hip_runtime.h>
#include <hip/hip_bf16.h>
#include <math.h>

#define NN 8192
typedef unsigned int u32;
typedef unsigned short u16;

__device__ __forceinline__ u32 bf16_rtne(float f) {
  u32 u = __float_as_uint(f);
  return (u + 0x7fffu + ((u >> 16) & 1u)) >> 16;
}
__device__ __forceinline__ float bf_lo(u32 d) { return __uint_as_float(d << 16); }
__device__ __forceinline__ float bf_hi(u32 d) { return __uint_as_float(d & 0xffff0000u); }

// ---------------------------------------------------------------------------
// Pass 1: h0 = adj_f32 @ [dfp,dts]; emit adj_bf16; fused MLP_l0 epilogue -> cur0
// 256 thr = 4 waves, wave owns 4 rows, lane owns k = k0+4l..+3 (float4 loads).
// ---------------------------------------------------------------------------
__global__ __launch_bounds__(256) void pass1_kernel(
    const float* __restrict__ adj, u16* __restrict__ adj16,
    const float* __restrict__ dfp, const float* __restrict__ dts,
    const float* __restrict__ W1, const float* __restrict__ b1,
    const float* __restrict__ W2, const float* __restrict__ b2,
    float* __restrict__ cur) {
  const int wave = threadIdx.x >> 6, lane = threadIdx.x & 63;
  const int row0 = blockIdx.x * 16 + wave * 4;
  float acc0[4] = {0.f, 0.f, 0.f, 0.f};
  float acc1[4] = {0.f, 0.f, 0.f, 0.f};

  float4 A[4], Xp, Xs;
  {
    const int k = 4 * lane;
    Xp = *(const float4*)(dfp + k);
    Xs = *(const float4*)(dts + k);
#pragma unroll
    for (int r = 0; r < 4; ++r)
      A[r] = *(const float4*)(adj + (size_t)(row0 + r) * NN + k);
  }
  for (int k0 = 0; k0 < NN; k0 += 256) {
    float4 B[4], Yp, Ys;
    if (k0 + 256 < NN) {  // prefetch next chunk (wave-uniform branch)
      const int k = k0 + 256 + 4 * lane;
      Yp = *(const float4*)(dfp + k);
      Ys = *(const float4*)(dts + k);
#pragma unroll
      for (int r = 0; r < 4; ++r)
        B[r] = *(const float4*)(adj + (size_t)(row0 + r) * NN + k);
    } else {
      Yp = Xp; Ys = Xs;
#pragma unroll
      for (int r = 0; r < 4; ++r) B[r] = A[r];
    }
    const int k = k0 + 4 * lane;
    const float pv[4] = {Xp.x, Xp.y, Xp.z, Xp.w};
    const float sv[4] = {Xs.x, Xs.y, Xs.z, Xs.w};
#pragma unroll
    for (int r = 0; r < 4; ++r) {
      const float av[4] = {A[r].x, A[r].y, A[r].z, A[r].w};
#pragma unroll
      for (int c = 0; c < 4; ++c) {
        acc0[r] = fmaf(av[c], pv[c], acc0[r]);
        acc1[r] = fmaf(av[c], sv[c], acc1[r]);
      }
      uint2 pk;
      pk.x = bf16_rtne(av[0]) | (bf16_rtne(av[1]) << 16);
      pk.y = bf16_rtne(av[2]) | (bf16_rtne(av[3]) << 16);
      *(uint2*)(adj16 + (size_t)(row0 + r) * NN + k) = pk;
    }
#pragma unroll
    for (int r = 0; r < 4; ++r) A[r] = B[r];
    Xp = Yp; Xs = Ys;
  }
  // full-wave butterfly: every lane ends with the complete row sums
#pragma unroll
  for (int r = 0; r < 4; ++r) {
    for (int off = 32; off; off >>= 1) {
      acc0[r] += __shfl_xor(acc0[r], off, 64);
      acc1[r] += __shfl_xor(acc1[r], off, 64);
    }
  }
  // fused MLP_l0: lanes 0..7 own output columns (lane&7 to avoid OOB W reads)
  const int j = lane & 7;
#pragma unroll
  for (int r = 0; r < 4; ++r) {
    float z = fmaf(acc0[r], W1[0 * 8 + j], fmaf(acc1[r], W1[1 * 8 + j], b1[j]));
    z = fmaxf(z, 0.f);
    float o = b2[j];
#pragma unroll
    for (int jj = 0; jj < 8; ++jj)
      o = fmaf(__shfl(z, jj, 64), W2[jj * 8 + j], o);
    if (lane < 8) cur[(size_t)(row0 + r) * 8 + j] = fmaxf(o, 0.f);
  }
}

// ---------------------------------------------------------------------------
// Passes 2/3: h = adj_bf16 @ x (x staged whole in LDS, transposed, bf16-packed,
// 128 KiB). 512 thr = 8 waves, wave owns 4 rows, lane owns k = k0+8l..+7
// (uint4 = 8 bf16 per load). HEADS=0: fused MLP_l1 -> cur1.
// HEADS=1: fused pol/val heads -> logits, value.
// ---------------------------------------------------------------------------
template <int HEADS>
__global__ __launch_bounds__(512) void pass23_kernel(
    const u16* __restrict__ adj16, const float* __restrict__ x,
    const float* __restrict__ W1, const float* __restrict__ b1,
    const float* __restrict__ W2, const float* __restrict__ b2,
    const float* __restrict__ W1v, const float* __restrict__ b1v,
    const float* __restrict__ W2v, const float* __restrict__ b2v,
    float* __restrict__ out0, float* __restrict__ out1) {
  __shared__ u32 xT[8][NN / 2];  // 128 KiB: xT[j] holds k-pairs packed bf16
  const int tid = threadIdx.x;
  const int wave = tid >> 6, lane = tid & 63;
  const int row0 = blockIdx.x * 32 + wave * 4;

  // issue first adj chunk loads early (overlap with staging + barrier)
  uint4 A[4];
#pragma unroll
  for (int r = 0; r < 4; ++r)
    A[r] = *(const uint4*)(adj16 + (size_t)(row0 + r) * NN + 8 * lane);

  // stage x -> LDS, transposed + bf16-packed (write pattern lane-contiguous)
  for (int p = tid; p < NN / 2; p += 512) {
    const float* r0 = x + (size_t)p * 16;
    float4 a0 = *(const float4*)(r0);
    float4 b0 = *(const float4*)(r0 + 4);
    float4 a1 = *(const float4*)(r0 + 8);
    float4 c1 = *(const float4*)(r0 + 12);
    const float e0[8] = {a0.x, a0.y, a0.z, a0.w, b0.x, b0.y, b0.z, b0.w};
    const float e1[8] = {a1.x, a1.y, a1.z, a1.w, c1.x, c1.y, c1.z, c1.w};
#pragma unroll
    for (int jj = 0; jj < 8; ++jj)
      xT[jj][p] = bf16_rtne(e0[jj]) | (bf16_rtne(e1[jj]) << 16);
  }
  __syncthreads();

  float acc[4][8] = {};
  for (int k0 = 0; k0 < NN; k0 += 512) {
    uint4 B[4];
    if (k0 + 512 < NN) {  // prefetch next chunk
#pragma unroll
      for (int r = 0; r < 4; ++r)
        B[r] = *(const uint4*)(adj16 + (size_t)(row0 + r) * NN + (k0 + 512) +
                               8 * lane);
    } else {
#pragma unroll
      for (int r = 0; r < 4; ++r) B[r] = A[r];
    }
    // x fragments from LDS: per j one b128, lane-contiguous (conflict-free)
    float xf[8][8];
#pragma unroll
    for (int jj = 0; jj < 8; ++jj) {
      uint4 xp = *((const uint4*)(&xT[jj][0]) + (k0 >> 3) + lane);
      xf[jj][0] = bf_lo(xp.x); xf[jj][1] = bf_hi(xp.x);
      xf[jj][2] = bf_lo(xp.y); xf[jj][3] = bf_hi(xp.y);
      xf[jj][4] = bf_lo(xp.z); xf[jj][5] = bf_hi(xp.z);
      xf[jj][6] = bf_lo(xp.w); xf[jj][7] = bf_hi(xp.w);
    }
#pragma unroll
    for (int r = 0; r < 4; ++r) {
      const u32 dw[4] = {A[r].x, A[r].y, A[r].z, A[r].w};
#pragma unroll
      for (int c = 0; c < 8; ++c) {
        const float a = (c & 1) ? bf_hi(dw[c >> 1]) : bf_lo(dw[c >> 1]);
#pragma unroll
        for (int jj = 0; jj < 8; ++jj)
          acc[r][jj] = fmaf(a, xf[jj][c], acc[r][jj]);
      }
    }
#pragma unroll
    for (int r = 0; r < 4; ++r) A[r] = B[r];
  }
  // butterfly: all lanes get full h[r][j]
#pragma unroll
  for (int r = 0; r < 4; ++r)
#pragma unroll
    for (int jj = 0; jj < 8; ++jj)
      for (int off = 32; off; off >>= 1)
        acc[r][jj] += __shfl_xor(acc[r][jj], off, 64);

  if (HEADS == 0) {
    const int j = lane & 7;
#pragma unroll
    for (int r = 0; r < 4; ++r) {
      float z = b1[j];
#pragma unroll
      for (int d = 0; d < 8; ++d) z = fmaf(acc[r][d], W1[d * 8 + j], z);
      z = fmaxf(z, 0.f);
      float o = b2[j];
#pragma unroll
      for (int jj = 0; jj < 8; ++jj)
        o = fmaf(__shfl(z, jj, 64), W2[jj * 8 + j], o);
      if (lane < 8) out0[(size_t)(row0 + r) * 8 + j] = fmaxf(o, 0.f);
    }
  } else {
    if (lane == 0) {
#pragma unroll
      for (int r = 0; r < 4; ++r) {
        float zp = b1[0], zv = b1v[0];
#pragma unroll
        for (int d = 0; d < 8; ++d) {
          zp = fmaf(acc[r][d], W1[d], zp);
          zv = fmaf(acc[r][d], W1v[d], zv);
        }
        zp = fmaxf(zp, 0.f);
        zv = fmaxf(zv, 0.f);
        out0[row0 + r] = fmaf(zp, W2[0], b2[0]);
        out1[row0 + r] = fmaf(zv, W2v[0], b2v[0]);
      }
    }
  }
}

// ---------------------------------------------------------------------------
// Reductions: max(logits), mean(value); then sumexp, var. scal = {m,1/e,mean,1/std}
// ---------------------------------------------------------------------------
__global__ __launch_bounds__(1024) void reduce_kernel(
    const float* __restrict__ logits, const float* __restrict__ value,
    float* __restrict__ scal) {
  const int tid = threadIdx.x, wave = tid >> 6, lane = tid & 63;
  __shared__ float sa[16], sb[16], sc[2];
  float m = -3.4e38f, s = 0.f;
#pragma unroll
  for (int it = 0; it < 2; ++it) {
    float4 l4 = *(const float4*)(logits + it * 4096 + tid * 4);
    float4 v4 = *(const float4*)(value + it * 4096 + tid * 4);
    m = fmaxf(m, fmaxf(fmaxf(l4.x, l4.y), fmaxf(l4.z, l4.w)));
    s += (v4.x + v4.y) + (v4.z + v4.w);
  }
  for (int off = 32; off; off >>= 1) {
    m = fmaxf(m, __shfl_xor(m, off, 64));
    s += __shfl_xor(s, off, 64);
  }
  if (lane == 0) { sa[wave] = m; sb[wave] = s; }
  __syncthreads();
  if (tid == 0) {
    float mm = sa[0], ss = sb[0];
    for (int i = 1; i < 16; ++i) { mm = fmaxf(mm, sa[i]); ss += sb[i]; }
    sc[0] = mm; sc[1] = ss * (1.f / NN);
  }
  __syncthreads();
  m = sc[0];
  const float mean = sc[1];
  float e = 0.f, v2 = 0.f;
#pragma unroll
  for (int it = 0; it < 2; ++it) {
    float4 l4 = *(const float4*)(logits + it * 4096 + tid * 4);
    float4 v4 = *(const float4*)(value + it * 4096 + tid * 4);
    e += expf(l4.x - m) + expf(l4.y - m) + expf(l4.z - m) + expf(l4.w - m);
    float d0 = v4.x - mean, d1 = v4.y - mean;
    float d2 = v4.z - mean, d3 = v4.w - mean;
    v2 = fmaf(d0, d0, v2); v2 = fmaf(d1, d1, v2);
    v2 = fmaf(d2, d2, v2); v2 = fmaf(d3, d3, v2);
  }
  for (int off = 32; off; off >>= 1) {
    e += __shfl_xor(e, off, 64);
    v2 += __shfl_xor(v2, off, 64);
  }
  if (lane == 0) { sa[wave] = e; sb[wave] = v2; }
  __syncthreads();
  if (tid == 0) {
    float ee = sa[0], vv = sb[0];
    for (int i = 1; i < 16; ++i) { ee += sa[i]; vv += sb[i]; }
    scal[0] = m;
    scal[1] = 1.f / ee;
    scal[2] = mean;
    scal[3] = 1.f / sqrtf(vv * (1.f / NN) + 1e-10f);
  }
}

__global__ __launch_bounds__(256) void finalize_kernel(
    float* __restrict__ out, const float* __restrict__ scal) {
  int i = blockIdx.x * 256 + threadIdx.x;
  if (i >= NN) return;
  float m = scal[0], inv_e = scal[1], mean = scal[2], inv_std = scal[3];
  out[i] = expf(out[i] - m) * inv_e;
  out[NN + i] = (out[NN + i] - mean) * inv_std;
}

// ---------------------------------------------------------------------------
extern "C" void kernel_launch(void* const* d_in, const int* in_sizes, int n_in,
                              void* d_out, int out_size, void* d_ws,
                              size_t ws_size, hipStream_t stream) {
  const float* adj = (const float*)d_in[0];
  const float* dfp = (const float*)d_in[1];
  const float* dts = (const float*)d_in[2];
  const float* W1_l0 = (const float*)d_in[3];
  const float* b1_l0 = (const float*)d_in[4];
  const float* W2_l0 = (const float*)d_in[5];
  const float* b2_l0 = (const float*)d_in[6];
  const float* W1_l1 = (const float*)d_in[7];
  const float* b1_l1 = (const float*)d_in[8];
  const float* W2_l1 = (const float*)d_in[9];
  const float* b2_l1 = (const float*)d_in[10];
  const float* W1_pol = (const float*)d_in[11];
  const float* b1_pol = (const float*)d_in[12];
  const float* W2_pol = (const float*)d_in[13];
  const float* b2_pol = (const float*)d_in[14];
  const float* W1_val = (const float*)d_in[15];
  const float* b1_val = (const float*)d_in[16];
  const float* W2_val = (const float*)d_in[17];
  const float* b2_val = (const float*)d_in[18];

  u16* adj16 = (u16*)d_ws;                                     // 128 MiB
  float* curA = (float*)((char*)d_ws + (size_t)NN * NN * 2);   // [N][8]
  float* curB = curA + NN * 8;                                 // [N][8]
  float* scal = curB + NN * 8;                                 // [4]
  float* logits = (float*)d_out;
  float* value = logits + NN;

  pass1_kernel<<<NN / 16, 256, 0, stream>>>(adj, adj16, dfp, dts, W1_l0, b1_l0,
                                            W2_l0, b2_l0, curA);
  pass23_kernel<0><<<NN / 32, 512, 0, stream>>>(
      adj16, curA, W1_l1, b1_l1, W2_l1, b2_l1, W1_l1, b1_l1, W2_l1, b2_l1,
      curB, curB);
  pass23_kernel<1><<<NN / 32, 512, 0, stream>>>(
      adj16, curB, W1_pol, b1_pol, W2_pol, b2_pol, W1_val, b1_val, W2_val,
      b2_val, logits, value);
  reduce_kernel<<<1, 1024, 0, stream>>>(logits, value, scal);
  finalize_kernel<<<32, 256, 0, stream>>>((float*)d_out, scal);
}

// Round 3
// 152.390 us; speedup vs baseline: 1.6306x; 1.0500x over previous
//
#include <hip/hip_runtime.h>
#include <hip/hip_bf16.h>
#include <math.h>

#define NN 8192
typedef unsigned int u32;
typedef unsigned char u8;

__device__ __forceinline__ u32 bf16_rtne(float f) {
  u32 u = __float_as_uint(f);
  return (u + 0x7fffu + ((u >> 16) & 1u)) >> 16;
}
__device__ __forceinline__ float bf_lo(u32 d) { return __uint_as_float(d << 16); }
__device__ __forceinline__ float bf_hi(u32 d) { return __uint_as_float(d & 0xffff0000u); }

// ---------------------------------------------------------------------------
// Pass 1: h0 = adj_f32 @ [dfp,dts] (exact f32); emit adj8 = round(adj*255);
// fused MLP_l0 epilogue -> cur0.  256 thr = 4 waves, wave owns 4 rows,
// lane owns k = k0 + 4*lane .. +3 (float4 loads, chunk=256).
// ---------------------------------------------------------------------------
__global__ __launch_bounds__(256) void pass1_kernel(
    const float* __restrict__ adj, u8* __restrict__ adj8,
    const float* __restrict__ dfp, const float* __restrict__ dts,
    const float* __restrict__ W1, const float* __restrict__ b1,
    const float* __restrict__ W2, const float* __restrict__ b2,
    float* __restrict__ cur) {
  const int wave = threadIdx.x >> 6, lane = threadIdx.x & 63;
  const int row0 = blockIdx.x * 16 + wave * 4;
  float acc0[4] = {0.f, 0.f, 0.f, 0.f};
  float acc1[4] = {0.f, 0.f, 0.f, 0.f};

  float4 A[4], Xp, Xs;
  {
    const int k = 4 * lane;
    Xp = *(const float4*)(dfp + k);
    Xs = *(const float4*)(dts + k);
#pragma unroll
    for (int r = 0; r < 4; ++r)
      A[r] = *(const float4*)(adj + (size_t)(row0 + r) * NN + k);
  }
  for (int k0 = 0; k0 < NN; k0 += 256) {
    float4 B[4], Yp, Ys;
    if (k0 + 256 < NN) {  // wave-uniform prefetch branch
      const int k = k0 + 256 + 4 * lane;
      Yp = *(const float4*)(dfp + k);
      Ys = *(const float4*)(dts + k);
#pragma unroll
      for (int r = 0; r < 4; ++r)
        B[r] = *(const float4*)(adj + (size_t)(row0 + r) * NN + k);
    } else {
      Yp = Xp; Ys = Xs;
#pragma unroll
      for (int r = 0; r < 4; ++r) B[r] = A[r];
    }
    const float pv[4] = {Xp.x, Xp.y, Xp.z, Xp.w};
    const float sv[4] = {Xs.x, Xs.y, Xs.z, Xs.w};
#pragma unroll
    for (int r = 0; r < 4; ++r) {
      const float av[4] = {A[r].x, A[r].y, A[r].z, A[r].w};
#pragma unroll
      for (int c = 0; c < 4; ++c) {
        acc0[r] = fmaf(av[c], pv[c], acc0[r]);
        acc1[r] = fmaf(av[c], sv[c], acc1[r]);
      }
      // quantize 4 entries to u8 fixed-point (scale 255), pack, store
      u32 q0 = (u32)fmaf(av[0], 255.f, 0.5f);
      u32 q1 = (u32)fmaf(av[1], 255.f, 0.5f);
      u32 q2 = (u32)fmaf(av[2], 255.f, 0.5f);
      u32 q3 = (u32)fmaf(av[3], 255.f, 0.5f);
      ((u32*)(adj8 + (size_t)(row0 + r) * NN + k0))[lane] =
          q0 | (q1 << 8) | (q2 << 16) | (q3 << 24);
    }
#pragma unroll
    for (int r = 0; r < 4; ++r) A[r] = B[r];
    Xp = Yp; Xs = Ys;
  }
  // full-wave butterfly: every lane ends with complete row sums
#pragma unroll
  for (int r = 0; r < 4; ++r) {
    for (int off = 32; off; off >>= 1) {
      acc0[r] += __shfl_xor(acc0[r], off, 64);
      acc1[r] += __shfl_xor(acc1[r], off, 64);
    }
  }
  const int j = lane & 7;
#pragma unroll
  for (int r = 0; r < 4; ++r) {
    float z = fmaf(acc0[r], W1[0 * 8 + j], fmaf(acc1[r], W1[1 * 8 + j], b1[j]));
    z = fmaxf(z, 0.f);
    float o = b2[j];
#pragma unroll
    for (int jj = 0; jj < 8; ++jj)
      o = fmaf(__shfl(z, jj, 64), W2[jj * 8 + j], o);
    if (lane < 8) cur[(size_t)(row0 + r) * 8 + j] = fmaxf(o, 0.f);
  }
}

// ---------------------------------------------------------------------------
// Passes 2/3: h = (adj8/255) @ x. Whole x staged in LDS transposed, packed
// bf16 pairs of x/255 (128 KiB). 512 thr = 8 waves, wave owns 4 rows; lane
// owns k = k0 + 16*lane .. +15 (uint4 = 16 int8), chunk = 1024 k, 8 chunks.
// HEADS=0: fused MLP_l1 -> cur1.  HEADS=1: fused pol/val heads.
// ---------------------------------------------------------------------------
template <int HEADS>
__global__ __launch_bounds__(512) void pass23_kernel(
    const u8* __restrict__ adj8, const float* __restrict__ x,
    const float* __restrict__ W1, const float* __restrict__ b1,
    const float* __restrict__ W2, const float* __restrict__ b2,
    const float* __restrict__ W1v, const float* __restrict__ b1v,
    const float* __restrict__ W2v, const float* __restrict__ b2v,
    float* __restrict__ out0, float* __restrict__ out1) {
  __shared__ u32 xT[8][NN / 2];  // 128 KiB: xT[j][p] = bf16 pair of x/255
  const int tid = threadIdx.x;
  const int wave = tid >> 6, lane = tid & 63;
  const int row0 = blockIdx.x * 32 + wave * 4;

  // issue first adj chunk early (overlaps staging + barrier)
  uint4 A[4];
#pragma unroll
  for (int r = 0; r < 4; ++r)
    A[r] = *(const uint4*)(adj8 + (size_t)(row0 + r) * NN + 16 * lane);

  // stage x -> LDS: transpose, prescale by 1/255, pack bf16 pairs
  const float inv255 = 1.f / 255.f;
  for (int p = tid; p < NN / 2; p += 512) {
    const float* r0 = x + (size_t)p * 16;
    float4 a0 = *(const float4*)(r0);
    float4 b0 = *(const float4*)(r0 + 4);
    float4 a1 = *(const float4*)(r0 + 8);
    float4 c1 = *(const float4*)(r0 + 12);
    const float e0[8] = {a0.x, a0.y, a0.z, a0.w, b0.x, b0.y, b0.z, b0.w};
    const float e1[8] = {a1.x, a1.y, a1.z, a1.w, c1.x, c1.y, c1.z, c1.w};
#pragma unroll
    for (int jj = 0; jj < 8; ++jj)
      xT[jj][p] = bf16_rtne(e0[jj] * inv255) | (bf16_rtne(e1[jj] * inv255) << 16);
  }
  __syncthreads();

  float acc[4][8] = {};
  for (int k0 = 0; k0 < NN; k0 += 1024) {
    uint4 B[4];
    if (k0 + 1024 < NN) {
#pragma unroll
      for (int r = 0; r < 4; ++r)
        B[r] = *(const uint4*)(adj8 + (size_t)(row0 + r) * NN + (k0 + 1024) +
                               16 * lane);
    } else {
#pragma unroll
      for (int r = 0; r < 4; ++r) B[r] = A[r];
    }
    // convert this chunk's adj bytes once: av[r][t], t = 0..15
    float av[4][16];
#pragma unroll
    for (int r = 0; r < 4; ++r) {
      const u32 dw[4] = {A[r].x, A[r].y, A[r].z, A[r].w};
#pragma unroll
      for (int t = 0; t < 16; ++t)
        av[r][t] = (float)((dw[t >> 2] >> (8 * (t & 3))) & 0xffu);
    }
    // per feature: unpack 16 x values (2 b128), FMA into 4 rows
    const u32* xrow;
#pragma unroll
    for (int jj = 0; jj < 8; ++jj) {
      xrow = &xT[jj][0];
      uint4 xp0 = *((const uint4*)xrow + (k0 >> 3) + 2 * lane);
      uint4 xp1 = *((const uint4*)xrow + (k0 >> 3) + 2 * lane + 1);
      float xf[16];
      xf[0] = bf_lo(xp0.x);  xf[1] = bf_hi(xp0.x);
      xf[2] = bf_lo(xp0.y);  xf[3] = bf_hi(xp0.y);
      xf[4] = bf_lo(xp0.z);  xf[5] = bf_hi(xp0.z);
      xf[6] = bf_lo(xp0.w);  xf[7] = bf_hi(xp0.w);
      xf[8] = bf_lo(xp1.x);  xf[9] = bf_hi(xp1.x);
      xf[10] = bf_lo(xp1.y); xf[11] = bf_hi(xp1.y);
      xf[12] = bf_lo(xp1.z); xf[13] = bf_hi(xp1.z);
      xf[14] = bf_lo(xp1.w); xf[15] = bf_hi(xp1.w);
#pragma unroll
      for (int r = 0; r < 4; ++r)
#pragma unroll
        for (int t = 0; t < 16; ++t)
          acc[r][jj] = fmaf(av[r][t], xf[t], acc[r][jj]);
    }
#pragma unroll
    for (int r = 0; r < 4; ++r) A[r] = B[r];
  }
  // butterfly: all lanes get full h[r][j]
#pragma unroll
  for (int r = 0; r < 4; ++r)
#pragma unroll
    for (int jj = 0; jj < 8; ++jj)
      for (int off = 32; off; off >>= 1)
        acc[r][jj] += __shfl_xor(acc[r][jj], off, 64);

  if (HEADS == 0) {
    const int j = lane & 7;
#pragma unroll
    for (int r = 0; r < 4; ++r) {
      float z = b1[j];
#pragma unroll
      for (int d = 0; d < 8; ++d) z = fmaf(acc[r][d], W1[d * 8 + j], z);
      z = fmaxf(z, 0.f);
      float o = b2[j];
#pragma unroll
      for (int jj = 0; jj < 8; ++jj)
        o = fmaf(__shfl(z, jj, 64), W2[jj * 8 + j], o);
      if (lane < 8) out0[(size_t)(row0 + r) * 8 + j] = fmaxf(o, 0.f);
    }
  } else {
    if (lane == 0) {
#pragma unroll
      for (int r = 0; r < 4; ++r) {
        float zp = b1[0], zv = b1v[0];
#pragma unroll
        for (int d = 0; d < 8; ++d) {
          zp = fmaf(acc[r][d], W1[d], zp);
          zv = fmaf(acc[r][d], W1v[d], zv);
        }
        zp = fmaxf(zp, 0.f);
        zv = fmaxf(zv, 0.f);
        out0[row0 + r] = fmaf(zp, W2[0], b2[0]);
        out1[row0 + r] = fmaf(zv, W2v[0], b2v[0]);
      }
    }
  }
}

// ---------------------------------------------------------------------------
// Fused reductions + finalize (single 1024-thr block; data stays in regs):
// phase1: max(logits), mean(value); phase2: sumexp, var; phase3: write
// policy and normalized value in place over d_out.
// ---------------------------------------------------------------------------
__global__ __launch_bounds__(1024) void reduce_finalize_kernel(
    float* __restrict__ out) {
  const int tid = threadIdx.x, wave = tid >> 6, lane = tid & 63;
  __shared__ float sa[16], sb[16], sc[4];

  float4 l0 = *(const float4*)(out + tid * 8);
  float4 l1 = *(const float4*)(out + tid * 8 + 4);
  float4 v0 = *(const float4*)(out + NN + tid * 8);
  float4 v1 = *(const float4*)(out + NN + tid * 8 + 4);
  const float lv[8] = {l0.x, l0.y, l0.z, l0.w, l1.x, l1.y, l1.z, l1.w};
  const float vv[8] = {v0.x, v0.y, v0.z, v0.w, v1.x, v1.y, v1.z, v1.w};

  float m = -3.4e38f, s = 0.f;
#pragma unroll
  for (int i = 0; i < 8; ++i) {
    m = fmaxf(m, lv[i]);
    s += vv[i];
  }
  for (int off = 32; off; off >>= 1) {
    m = fmaxf(m, __shfl_xor(m, off, 64));
    s += __shfl_xor(s, off, 64);
  }
  if (lane == 0) { sa[wave] = m; sb[wave] = s; }
  __syncthreads();
  if (tid == 0) {
    float mm = sa[0], ss = sb[0];
    for (int i = 1; i < 16; ++i) { mm = fmaxf(mm, sa[i]); ss += sb[i]; }
    sc[0] = mm; sc[1] = ss * (1.f / NN);
  }
  __syncthreads();
  m = sc[0];
  const float mean = sc[1];

  float el[8];
  float e = 0.f, v2 = 0.f;
#pragma unroll
  for (int i = 0; i < 8; ++i) {
    el[i] = expf(lv[i] - m);
    e += el[i];
    float d = vv[i] - mean;
    v2 = fmaf(d, d, v2);
  }
  for (int off = 32; off; off >>= 1) {
    e += __shfl_xor(e, off, 64);
    v2 += __shfl_xor(v2, off, 64);
  }
  if (lane == 0) { sa[wave] = e; sb[wave] = v2; }
  __syncthreads();
  if (tid == 0) {
    float ee = sa[0], vvv = sb[0];
    for (int i = 1; i < 16; ++i) { ee += sa[i]; vvv += sb[i]; }
    sc[2] = 1.f / ee;
    sc[3] = 1.f / sqrtf(vvv * (1.f / NN) + 1e-10f);
  }
  __syncthreads();
  const float inv_e = sc[2], inv_std = sc[3];
  float4 o0, o1, w0, w1;
  o0.x = el[0] * inv_e; o0.y = el[1] * inv_e;
  o0.z = el[2] * inv_e; o0.w = el[3] * inv_e;
  o1.x = el[4] * inv_e; o1.y = el[5] * inv_e;
  o1.z = el[6] * inv_e; o1.w = el[7] * inv_e;
  w0.x = (vv[0] - mean) * inv_std; w0.y = (vv[1] - mean) * inv_std;
  w0.z = (vv[2] - mean) * inv_std; w0.w = (vv[3] - mean) * inv_std;
  w1.x = (vv[4] - mean) * inv_std; w1.y = (vv[5] - mean) * inv_std;
  w1.z = (vv[6] - mean) * inv_std; w1.w = (vv[7] - mean) * inv_std;
  *(float4*)(out + tid * 8) = o0;
  *(float4*)(out + tid * 8 + 4) = o1;
  *(float4*)(out + NN + tid * 8) = w0;
  *(float4*)(out + NN + tid * 8 + 4) = w1;
}

// ---------------------------------------------------------------------------
extern "C" void kernel_launch(void* const* d_in, const int* in_sizes, int n_in,
                              void* d_out, int out_size, void* d_ws,
                              size_t ws_size, hipStream_t stream) {
  const float* adj = (const float*)d_in[0];
  const float* dfp = (const float*)d_in[1];
  const float* dts = (const float*)d_in[2];
  const float* W1_l0 = (const float*)d_in[3];
  const float* b1_l0 = (const float*)d_in[4];
  const float* W2_l0 = (const float*)d_in[5];
  const float* b2_l0 = (const float*)d_in[6];
  const float* W1_l1 = (const float*)d_in[7];
  const float* b1_l1 = (const float*)d_in[8];
  const float* W2_l1 = (const float*)d_in[9];
  const float* b2_l1 = (const float*)d_in[10];
  const float* W1_pol = (const float*)d_in[11];
  const float* b1_pol = (const float*)d_in[12];
  const float* W2_pol = (const float*)d_in[13];
  const float* b2_pol = (const float*)d_in[14];
  const float* W1_val = (const float*)d_in[15];
  const float* b1_val = (const float*)d_in[16];
  const float* W2_val = (const float*)d_in[17];
  const float* b2_val = (const float*)d_in[18];

  u8* adj8 = (u8*)d_ws;                                       // 64 MiB
  float* curA = (float*)((char*)d_ws + (size_t)NN * NN);      // [N][8]
  float* curB = curA + NN * 8;                                // [N][8]
  float* logits = (float*)d_out;
  float* value = logits + NN;

  pass1_kernel<<<NN / 16, 256, 0, stream>>>(adj, adj8, dfp, dts, W1_l0, b1_l0,
                                            W2_l0, b2_l0, curA);
  pass23_kernel<0><<<NN / 32, 512, 0, stream>>>(
      adj8, curA, W1_l1, b1_l1, W2_l1, b2_l1, W1_l1, b1_l1, W2_l1, b2_l1,
      curB, curB);
  pass23_kernel<1><<<NN / 32, 512, 0, stream>>>(
      adj8, curB, W1_pol, b1_pol, W2_pol, b2_pol, W1_val, b1_val, W2_val,
      b2_val, logits, value);
  reduce_finalize_kernel<<<1, 1024, 0, stream>>>((float*)d_out);
}

// Round 4
// 145.861 us; speedup vs baseline: 1.7036x; 1.0448x over previous
//
#include <hip/hip_runtime.h>
#include <math.h>

#define NN 8192
typedef unsigned int u32;
typedef unsigned char u8;

__device__ __forceinline__ u32 dot4(u32 a, u32 b, u32 c) {
#if __has_builtin(__builtin_amdgcn_udot4)
  return __builtin_amdgcn_udot4(a, b, c, false);
#else
  c += (a & 0xffu) * (b & 0xffu);
  c += ((a >> 8) & 0xffu) * ((b >> 8) & 0xffu);
  c += ((a >> 16) & 0xffu) * ((b >> 16) & 0xffu);
  c += (a >> 24) * (b >> 24);
  return c;
#endif
}

// ---------------------------------------------------------------------------
// Pass 1: h0 = adj_f32 @ [dfp,dts] (exact f32); emit adj8 = round(adj*255);
// fused MLP_l0 -> cur0; per-block feature-max partials for x-quantization.
// 512 blocks x 256 thr; wave owns 4 rows; lane owns k = k0+4*lane..+3.
// ---------------------------------------------------------------------------
__global__ __launch_bounds__(256) void pass1_kernel(
    const float* __restrict__ adj, u8* __restrict__ adj8,
    const float* __restrict__ dfp, const float* __restrict__ dts,
    const float* __restrict__ W1, const float* __restrict__ b1,
    const float* __restrict__ W2, const float* __restrict__ b2,
    float* __restrict__ cur, float* __restrict__ partial) {
  const int wave = threadIdx.x >> 6, lane = threadIdx.x & 63;
  const int row0 = blockIdx.x * 16 + wave * 4;
  __shared__ float w1red[4][8];
  float acc0[4] = {0.f, 0.f, 0.f, 0.f};
  float acc1[4] = {0.f, 0.f, 0.f, 0.f};

  float4 A[4], Xp, Xs;
  {
    const int k = 4 * lane;
    Xp = *(const float4*)(dfp + k);
    Xs = *(const float4*)(dts + k);
#pragma unroll
    for (int r = 0; r < 4; ++r)
      A[r] = *(const float4*)(adj + (size_t)(row0 + r) * NN + k);
  }
  for (int k0 = 0; k0 < NN; k0 += 256) {
    float4 B[4], Yp, Ys;
    if (k0 + 256 < NN) {  // wave-uniform prefetch branch
      const int k = k0 + 256 + 4 * lane;
      Yp = *(const float4*)(dfp + k);
      Ys = *(const float4*)(dts + k);
#pragma unroll
      for (int r = 0; r < 4; ++r)
        B[r] = *(const float4*)(adj + (size_t)(row0 + r) * NN + k);
    } else {
      Yp = Xp; Ys = Xs;
#pragma unroll
      for (int r = 0; r < 4; ++r) B[r] = A[r];
    }
    const float pv[4] = {Xp.x, Xp.y, Xp.z, Xp.w};
    const float sv[4] = {Xs.x, Xs.y, Xs.z, Xs.w};
#pragma unroll
    for (int r = 0; r < 4; ++r) {
      const float av[4] = {A[r].x, A[r].y, A[r].z, A[r].w};
#pragma unroll
      for (int c = 0; c < 4; ++c) {
        acc0[r] = fmaf(av[c], pv[c], acc0[r]);
        acc1[r] = fmaf(av[c], sv[c], acc1[r]);
      }
      u32 q0 = (u32)fmaf(av[0], 255.f, 0.5f);
      u32 q1 = (u32)fmaf(av[1], 255.f, 0.5f);
      u32 q2 = (u32)fmaf(av[2], 255.f, 0.5f);
      u32 q3 = (u32)fmaf(av[3], 255.f, 0.5f);
      ((u32*)(adj8 + (size_t)(row0 + r) * NN + k0))[lane] =
          q0 | (q1 << 8) | (q2 << 16) | (q3 << 24);
    }
#pragma unroll
    for (int r = 0; r < 4; ++r) A[r] = B[r];
    Xp = Yp; Xs = Ys;
  }
#pragma unroll
  for (int r = 0; r < 4; ++r) {
    for (int off = 32; off; off >>= 1) {
      acc0[r] += __shfl_xor(acc0[r], off, 64);
      acc1[r] += __shfl_xor(acc1[r], off, 64);
    }
  }
  const int j = lane & 7;
  float mx = 0.f;
#pragma unroll
  for (int r = 0; r < 4; ++r) {
    float z = fmaf(acc0[r], W1[0 * 8 + j], fmaf(acc1[r], W1[1 * 8 + j], b1[j]));
    z = fmaxf(z, 0.f);
    float o = b2[j];
#pragma unroll
    for (int jj = 0; jj < 8; ++jj)
      o = fmaf(__shfl(z, jj, 64), W2[jj * 8 + j], o);
    float val = fmaxf(o, 0.f);
    if (lane < 8) cur[(size_t)(row0 + r) * 8 + j] = val;
    mx = fmaxf(mx, val);
  }
  if (lane < 8) w1red[wave][lane] = mx;
  __syncthreads();
  if (wave == 0 && lane < 8) {
    float m2 = fmaxf(fmaxf(w1red[0][lane], w1red[1][lane]),
                     fmaxf(w1red[2][lane], w1red[3][lane]));
    partial[blockIdx.x * 8 + lane] = m2;
  }
}

// ---------------------------------------------------------------------------
// Passes 2/3: h = (adj8/255) @ x via integer udot4 (exact i32 accumulation).
// x quantized per-feature to u8 (scale from producer's partial maxes), staged
// in LDS feature-major. 256 blocks x 512 thr (8 waves x 4 rows = 32 rows/blk).
// Lane owns k = k0+16*lane..+15 (uint4 adj + uint4 x per feature), chunk=1024.
// HEADS=0: fused MLP_l1 -> cur1 + partialB.  HEADS=1: fused pol/val heads.
// ---------------------------------------------------------------------------
template <int HEADS>
__global__ __launch_bounds__(512) void pass23_kernel(
    const u8* __restrict__ adj8, const float* __restrict__ x,
    const float* __restrict__ partial, int nprod,
    const float* __restrict__ W1, const float* __restrict__ b1,
    const float* __restrict__ W2, const float* __restrict__ b2,
    const float* __restrict__ W1v, const float* __restrict__ b1v,
    const float* __restrict__ W2v, const float* __restrict__ b2v,
    float* __restrict__ out0, float* __restrict__ out1,
    float* __restrict__ partial_out) {
  __shared__ u32 sxR[NN * 2];     // 64 KiB: row-major x_q, [row] = 8 bytes
  __shared__ u32 sxT[8 * 2048];   // 64 KiB: feature-major, [j][k/4] u32
  __shared__ float swred[8][8];
  __shared__ float sqs[8], sds[8];
  const int tid = threadIdx.x;
  const int wave = tid >> 6, lane = tid & 63;
  const int row0 = blockIdx.x * 32 + wave * 4;

  // issue first adj chunk early (overlaps scale-reduce + staging)
  uint4 A[4];
#pragma unroll
  for (int r = 0; r < 4; ++r)
    A[r] = *(const uint4*)(adj8 + (size_t)(row0 + r) * NN + 16 * lane);

  // --- per-feature max from producer partials -> quant/dequant scales ---
  float pm[8] = {0.f, 0.f, 0.f, 0.f, 0.f, 0.f, 0.f, 0.f};
  if (tid < nprod) {
    float4 a = *(const float4*)(partial + tid * 8);
    float4 b = *(const float4*)(partial + tid * 8 + 4);
    pm[0] = a.x; pm[1] = a.y; pm[2] = a.z; pm[3] = a.w;
    pm[4] = b.x; pm[5] = b.y; pm[6] = b.z; pm[7] = b.w;
  }
  for (int off = 32; off; off >>= 1)
#pragma unroll
    for (int j = 0; j < 8; ++j) pm[j] = fmaxf(pm[j], __shfl_xor(pm[j], off, 64));
  if (lane == 0)
#pragma unroll
    for (int j = 0; j < 8; ++j) swred[wave][j] = pm[j];
  __syncthreads();
  if (tid < 8) {
    float m2 = 0.f;
#pragma unroll
    for (int w = 0; w < 8; ++w) m2 = fmaxf(m2, swred[w][tid]);
    m2 = fmaxf(m2, 1e-20f);
    sqs[tid] = 255.f / m2;
    sds[tid] = m2 / 65025.f;
  }
  __syncthreads();

  // --- stage A: quantize x rows -> sxR (coalesced) ---
  float qs[8];
#pragma unroll
  for (int j = 0; j < 8; ++j) qs[j] = sqs[j];
  for (int base = 0; base < NN; base += 512) {
    const int row = base + tid;
    float4 a = *(const float4*)(x + (size_t)row * 8);
    float4 b = *(const float4*)(x + (size_t)row * 8 + 4);
    u32 q0 = (u32)fmaf(a.x, qs[0], 0.5f), q1 = (u32)fmaf(a.y, qs[1], 0.5f);
    u32 q2 = (u32)fmaf(a.z, qs[2], 0.5f), q3 = (u32)fmaf(a.w, qs[3], 0.5f);
    u32 q4 = (u32)fmaf(b.x, qs[4], 0.5f), q5 = (u32)fmaf(b.y, qs[5], 0.5f);
    u32 q6 = (u32)fmaf(b.z, qs[6], 0.5f), q7 = (u32)fmaf(b.w, qs[7], 0.5f);
    uint2 pk;
    pk.x = q0 | (q1 << 8) | (q2 << 16) | (q3 << 24);
    pk.y = q4 | (q5 << 8) | (q6 << 16) | (q7 << 24);
    ((uint2*)sxR)[row] = pk;
  }
  __syncthreads();

  // --- stage B: transpose to feature-major sxT[j][k/4] ---
  {
    const int jj = tid & 7, g = tid >> 3;  // g in 0..63
    const int dw = jj >> 2, sh = 8 * (jj & 3);
#pragma unroll
    for (int i = 0; i < 32; ++i) {
      const int p = g + 64 * i;  // 0..2047
      u32 w = 0;
#pragma unroll
      for (int m = 0; m < 4; ++m)
        w |= (((sxR[(4 * p + m) * 2 + dw] >> sh) & 0xffu) << (8 * m));
      sxT[jj * 2048 + p] = w;
    }
  }
  __syncthreads();

  // --- main loop: integer dot4 ---
  u32 acc[4][8] = {};
  for (int k0 = 0; k0 < NN; k0 += 1024) {
    uint4 B[4];
    if (k0 + 1024 < NN) {
#pragma unroll
      for (int r = 0; r < 4; ++r)
        B[r] = *(const uint4*)(adj8 + (size_t)(row0 + r) * NN + (k0 + 1024) +
                               16 * lane);
    } else {
#pragma unroll
      for (int r = 0; r < 4; ++r) B[r] = A[r];
    }
    uint4 xq[8];
#pragma unroll
    for (int jj = 0; jj < 8; ++jj)
      xq[jj] = ((const uint4*)sxT)[jj * 512 + (k0 >> 4) + lane];
#pragma unroll
    for (int r = 0; r < 4; ++r) {
#pragma unroll
      for (int jj = 0; jj < 8; ++jj) {
        u32 c = acc[r][jj];
        c = dot4(A[r].x, xq[jj].x, c);
        c = dot4(A[r].y, xq[jj].y, c);
        c = dot4(A[r].z, xq[jj].z, c);
        c = dot4(A[r].w, xq[jj].w, c);
        acc[r][jj] = c;
      }
    }
#pragma unroll
    for (int r = 0; r < 4; ++r) A[r] = B[r];
  }
  // butterfly (integer) -> all lanes hold full sums; dequantize
#pragma unroll
  for (int r = 0; r < 4; ++r)
#pragma unroll
    for (int jj = 0; jj < 8; ++jj)
      for (int off = 32; off; off >>= 1)
        acc[r][jj] += (u32)__shfl_xor((int)acc[r][jj], off, 64);
  float dsc[8];
#pragma unroll
  for (int j = 0; j < 8; ++j) dsc[j] = sds[j];
  float h[4][8];
#pragma unroll
  for (int r = 0; r < 4; ++r)
#pragma unroll
    for (int jj = 0; jj < 8; ++jj) h[r][jj] = (float)acc[r][jj] * dsc[jj];

  if (HEADS == 0) {
    const int j = lane & 7;
    float mxv = 0.f;
#pragma unroll
    for (int r = 0; r < 4; ++r) {
      float z = b1[j];
#pragma unroll
      for (int d = 0; d < 8; ++d) z = fmaf(h[r][d], W1[d * 8 + j], z);
      z = fmaxf(z, 0.f);
      float o = b2[j];
#pragma unroll
      for (int jj = 0; jj < 8; ++jj)
        o = fmaf(__shfl(z, jj, 64), W2[jj * 8 + j], o);
      float val = fmaxf(o, 0.f);
      if (lane < 8) out0[(size_t)(row0 + r) * 8 + j] = val;
      mxv = fmaxf(mxv, val);
    }
    if (lane < 8) swred[wave][lane] = mxv;
    __syncthreads();
    if (wave == 0 && lane < 8) {
      float m2 = 0.f;
#pragma unroll
      for (int w = 0; w < 8; ++w) m2 = fmaxf(m2, swred[w][lane]);
      partial_out[blockIdx.x * 8 + lane] = m2;
    }
  } else {
    if (lane == 0) {
#pragma unroll
      for (int r = 0; r < 4; ++r) {
        float zp = b1[0], zv = b1v[0];
#pragma unroll
        for (int d = 0; d < 8; ++d) {
          zp = fmaf(h[r][d], W1[d], zp);
          zv = fmaf(h[r][d], W1v[d], zv);
        }
        zp = fmaxf(zp, 0.f);
        zv = fmaxf(zv, 0.f);
        out0[row0 + r] = fmaf(zp, W2[0], b2[0]);
        out1[row0 + r] = fmaf(zv, W2v[0], b2v[0]);
      }
    }
  }
}

// ---------------------------------------------------------------------------
// Fused reductions + finalize (single 1024-thr block; data stays in regs).
// ---------------------------------------------------------------------------
__global__ __launch_bounds__(1024) void reduce_finalize_kernel(
    float* __restrict__ out) {
  const int tid = threadIdx.x, wave = tid >> 6, lane = tid & 63;
  __shared__ float sa[16], sb[16], sc[4];

  float4 l0 = *(const float4*)(out + tid * 8);
  float4 l1 = *(const float4*)(out + tid * 8 + 4);
  float4 v0 = *(const float4*)(out + NN + tid * 8);
  float4 v1 = *(const float4*)(out + NN + tid * 8 + 4);
  const float lv[8] = {l0.x, l0.y, l0.z, l0.w, l1.x, l1.y, l1.z, l1.w};
  const float vv[8] = {v0.x, v0.y, v0.z, v0.w, v1.x, v1.y, v1.z, v1.w};

  float m = -3.4e38f, s = 0.f;
#pragma unroll
  for (int i = 0; i < 8; ++i) {
    m = fmaxf(m, lv[i]);
    s += vv[i];
  }
  for (int off = 32; off; off >>= 1) {
    m = fmaxf(m, __shfl_xor(m, off, 64));
    s += __shfl_xor(s, off, 64);
  }
  if (lane == 0) { sa[wave] = m; sb[wave] = s; }
  __syncthreads();
  if (tid == 0) {
    float mm = sa[0], ss = sb[0];
    for (int i = 1; i < 16; ++i) { mm = fmaxf(mm, sa[i]); ss += sb[i]; }
    sc[0] = mm; sc[1] = ss * (1.f / NN);
  }
  __syncthreads();
  m = sc[0];
  const float mean = sc[1];

  float el[8];
  float e = 0.f, v2 = 0.f;
#pragma unroll
  for (int i = 0; i < 8; ++i) {
    el[i] = expf(lv[i] - m);
    e += el[i];
    float d = vv[i] - mean;
    v2 = fmaf(d, d, v2);
  }
  for (int off = 32; off; off >>= 1) {
    e += __shfl_xor(e, off, 64);
    v2 += __shfl_xor(v2, off, 64);
  }
  if (lane == 0) { sa[wave] = e; sb[wave] = v2; }
  __syncthreads();
  if (tid == 0) {
    float ee = sa[0], vvv = sb[0];
    for (int i = 1; i < 16; ++i) { ee += sa[i]; vvv += sb[i]; }
    sc[2] = 1.f / ee;
    sc[3] = 1.f / sqrtf(vvv * (1.f / NN) + 1e-10f);
  }
  __syncthreads();
  const float inv_e = sc[2], inv_std = sc[3];
  float4 o0, o1, w0, w1;
  o0.x = el[0] * inv_e; o0.y = el[1] * inv_e;
  o0.z = el[2] * inv_e; o0.w = el[3] * inv_e;
  o1.x = el[4] * inv_e; o1.y = el[5] * inv_e;
  o1.z = el[6] * inv_e; o1.w = el[7] * inv_e;
  w0.x = (vv[0] - mean) * inv_std; w0.y = (vv[1] - mean) * inv_std;
  w0.z = (vv[2] - mean) * inv_std; w0.w = (vv[3] - mean) * inv_std;
  w1.x = (vv[4] - mean) * inv_std; w1.y = (vv[5] - mean) * inv_std;
  w1.z = (vv[6] - mean) * inv_std; w1.w = (vv[7] - mean) * inv_std;
  *(float4*)(out + tid * 8) = o0;
  *(float4*)(out + tid * 8 + 4) = o1;
  *(float4*)(out + NN + tid * 8) = w0;
  *(float4*)(out + NN + tid * 8 + 4) = w1;
}

// ---------------------------------------------------------------------------
extern "C" void kernel_launch(void* const* d_in, const int* in_sizes, int n_in,
                              void* d_out, int out_size, void* d_ws,
                              size_t ws_size, hipStream_t stream) {
  const float* adj = (const float*)d_in[0];
  const float* dfp = (const float*)d_in[1];
  const float* dts = (const float*)d_in[2];
  const float* W1_l0 = (const float*)d_in[3];
  const float* b1_l0 = (const float*)d_in[4];
  const float* W2_l0 = (const float*)d_in[5];
  const float* b2_l0 = (const float*)d_in[6];
  const float* W1_l1 = (const float*)d_in[7];
  const float* b1_l1 = (const float*)d_in[8];
  const float* W2_l1 = (const float*)d_in[9];
  const float* b2_l1 = (const float*)d_in[10];
  const float* W1_pol = (const float*)d_in[11];
  const float* b1_pol = (const float*)d_in[12];
  const float* W2_pol = (const float*)d_in[13];
  const float* b2_pol = (const float*)d_in[14];
  const float* W1_val = (const float*)d_in[15];
  const float* b1_val = (const float*)d_in[16];
  const float* W2_val = (const float*)d_in[17];
  const float* b2_val = (const float*)d_in[18];

  u8* adj8 = (u8*)d_ws;                                   // 64 MiB
  float* curA = (float*)((char*)d_ws + (size_t)NN * NN);  // [N][8]
  float* curB = curA + NN * 8;
  float* partialA = curB + NN * 8;   // [512][8]
  float* partialB = partialA + 512 * 8;  // [256][8]
  float* logits = (float*)d_out;
  float* value = logits + NN;

  pass1_kernel<<<NN / 16, 256, 0, stream>>>(adj, adj8, dfp, dts, W1_l0, b1_l0,
                                            W2_l0, b2_l0, curA, partialA);
  pass23_kernel<0><<<NN / 32, 512, 0, stream>>>(
      adj8, curA, partialA, 512, W1_l1, b1_l1, W2_l1, b2_l1, W1_l1, b1_l1,
      W2_l1, b2_l1, curB, curB, partialB);
  pass23_kernel<1><<<NN / 32, 512, 0, stream>>>(
      adj8, curB, partialB, 256, W1_pol, b1_pol, W2_pol, b2_pol, W1_val,
      b1_val, W2_val, b2_val, logits, value, partialB);
  reduce_finalize_kernel<<<1, 1024, 0, stream>>>((float*)d_out);
}